// Round 7
// baseline (148.063 us; speedup 1.0000x reference)
//
#include <hip/hip_runtime.h>
#include <math.h>

#define NCAM 6
#define CCH  64
#define DB   66
#define FH   32
#define FW   88
#define NX   128
#define NY   128
#define NZ   8
#define NPTS (NX*NY*NZ)
#define NPIX (NCAM*FH*FW)
#define PPC  (FH*FW)          // pixels per camera = 2816

// ---------------------------------------------------------------------------
// Kernel 1 v4: pixel-per-lane depth-net. 132 blocks x 256 thr; block = 128
// contiguous pixels of one camera (2816/128 = 22 blocks/cam). Waves 0-1:
// depth head (66 outs, y[] in regs, in-register softmax, transposed
// coalesced stores to depth_T[d][pix]). Waves 2-3: feat head (64 outs,
// streamed, LDS-transposed to coalesced feat_t[pix][ch] stores).
// Weights/bias are wave-uniform -> scalar (s_load) reads; no LDS staging,
// no barriers except the final transpose fence.
// ---------------------------------------------------------------------------
__global__ __launch_bounds__(256, 1) void depthnet_kernel(
    const float* __restrict__ x_fov, const float* __restrict__ w_dn,
    const float* __restrict__ b_dn, float* __restrict__ feat_t,
    float* __restrict__ depth_T)
{
    __shared__ float fl[128 * 65];          // feat transpose buffer (33.3 KB)
    const int t    = threadIdx.x;
    const int wid  = t >> 6;
    const int lane = t & 63;
    const int pxl  = (wid & 1) * 64 + lane; // 0..127 local pixel
    const int pg   = blockIdx.x * 128 + pxl; // global pixel id
    const int cam  = blockIdx.x / 22;
    const int p    = pg - cam * PPC;        // pixel within camera

    // x[64] in VGPRs: per-channel coalesced 256B loads
    const float* xf = x_fov + (size_t)cam * CCH * PPC + p;
    float x[64];
    #pragma unroll
    for (int c = 0; c < 64; ++c) x[c] = xf[(size_t)c * PPC];

    if (wid < 2) {
        // ---- depth head: 66 outputs, in-register softmax ----
        float y[DB];
        #pragma unroll
        for (int o = 0; o < DB; ++o) {
            float a = b_dn[o];
            #pragma unroll
            for (int c = 0; c < 64; ++c) a = fmaf(w_dn[o * 64 + c], x[c], a);
            y[o] = a;
        }
        float m = y[0];
        #pragma unroll
        for (int o = 1; o < DB; ++o) m = fmaxf(m, y[o]);
        float ssum = 0.f;
        #pragma unroll
        for (int o = 0; o < DB; ++o) { y[o] = expf(y[o] - m); ssum += y[o]; }
        const float inv = 1.f / ssum;
        #pragma unroll
        for (int o = 0; o < DB; ++o)
            depth_T[(size_t)o * NPIX + pg] = y[o] * inv;   // coalesced per o
    } else {
        // ---- feat head: 64 outputs, streamed into LDS transpose buffer ----
        #pragma unroll
        for (int o = 0; o < CCH; ++o) {
            float a = b_dn[DB + o];
            #pragma unroll
            for (int c = 0; c < 64; ++c) a = fmaf(w_dn[(DB + o) * 64 + c], x[c], a);
            fl[pxl * 65 + o] = a;           // +1 pad: conflict-free scatter
        }
    }
    __syncthreads();

    // cooperative coalesced feat store: 128 px x 64 ch
    const size_t fbase = (size_t)blockIdx.x * 128 * CCH;
    for (int i = t; i < 128 * CCH; i += 256) {
        const int px = i >> 6, o = i & 63;
        feat_t[fbase + i] = fl[px * 65 + o];
    }
}

// ---------------------------------------------------------------------------
// Kernel 2: wave = 8 points (one (ix,iy) column, g = iz) x 8 lanes.
// Lane s computes camera s's projection (no redundancy), broadcast by shfl.
// Per corner: 8-lane group loads 64 channels as 2x float4 (256B contiguous).
// Depth is TRANSPOSED [d][pix]: corner x0,x0+1 taps are adjacent floats ->
// half the depth-tap requests. Block = 4 consecutive iy at one ix; final
// LDS transpose makes stores full 128-B lines.
// ---------------------------------------------------------------------------
__global__ __launch_bounds__(256) void splat_kernel(
    const float* __restrict__ feat_t, const float* __restrict__ depth_T,
    const float* __restrict__ proj, float* __restrict__ out)
{
    __shared__ float trans[64 * 33];      // 8448 B, +1-pad stride
    const int t    = threadIdx.x;
    const int w    = t >> 6;              // wave in block: iy offset 0..3
    const int lane = t & 63;
    const int g    = lane >> 3;           // iz
    const int s    = lane & 7;            // sub-lane
    const int gb   = lane & 56;           // group base lane
    const int ix   = blockIdx.x >> 5;     // 0..127
    const int iy0  = 4 * (blockIdx.x & 31);
    const int iy   = iy0 + w;

    // bit-exact numpy voxel-center grid (double -> float)
    const double DXY = 102.4 / 128.0;
    const float px = (float)(-51.2 + (ix + 0.5) * DXY);
    const float py = (float)(-51.2 + (iy + 0.5) * DXY);
    const float pz = (float)(-5.0 + (g + 0.5) * 1.0);

    // ---- Stage 1: lane s projects this group's point into camera s -------
    float gxs = 0.f, gys = 0.f, gzs = -1e3f;
    bool validm = false;
    if (s < NCAM) {
        const float* M = proj + s * 16;
        const float u4 = M[0] * px + M[1] * py + M[2]  * pz + M[3];
        const float v4 = M[4] * px + M[5] * py + M[6]  * pz + M[7];
        const float z  = M[8] * px + M[9] * py + M[10] * pz + M[11];
        const float zs = fabsf(z) > 0.001f ? z : 0.001f;
        const float u = u4 / zs;
        const float v = v4 / zs;
        validm = (u >= 0.f) && (u < 1408.f) && (v >= 0.f) && (v < 512.f) &&
                 (z > 0.f) && (z < 50.f);
        if (validm) {
            gxs = u / 1408.0f * (float)FW - 0.5f;
            gys = v / 512.0f  * (float)FH - 0.5f;
            gzs = z / 50.0f   * (float)DB - 0.5f;
        }
    }
    const unsigned long long bal = __ballot(validm);
    const float cnt = (float)__popcll((bal >> (g * 8)) & 0x3Full);

    float acc[8];
    #pragma unroll
    for (int a = 0; a < 8; ++a) acc[a] = 0.f;

    // ---- Stage 2: per camera, group-uniform gather ------------------------
    for (int cam = 0; cam < NCAM; ++cam) {
        const float gx = __shfl(gxs, gb | cam);
        const float gy = __shfl(gys, gb | cam);
        const float gz = __shfl(gzs, gb | cam);
        if (gz < -500.f) continue;        // exec-masked; skipped if no group valid

        const float xf = floorf(gx), yf = floorf(gy), zf = floorf(gz);
        const float tx = gx - xf, ty = gy - yf, tz = gz - zf;
        const int x0 = (int)xf, y0 = (int)yf, z0 = (int)zf;

        const float wz0 = (z0 >= 0 && z0 < DB) ? (1.f - tz) : 0.f;
        const float wz1 = (z0 + 1 < DB) ? tz : 0.f;
        const int zi0 = min(max(z0, 0), DB - 1);
        const int zi1 = min(max(z0 + 1, 0), DB - 1);

        float wcorn[4];
        int   pixc[4];
        #pragma unroll
        for (int dy = 0; dy < 2; ++dy) {
            const int yi = y0 + dy;
            const bool yin = (yi >= 0) & (yi < FH);
            const int yic = min(max(yi, 0), FH - 1);
            const float wy = (dy ? ty : 1.f - ty) * (yin ? 1.f : 0.f);
            #pragma unroll
            for (int dx = 0; dx < 2; ++dx) {
                const int xi = x0 + dx;
                const bool xin = (xi >= 0) & (xi < FW);
                const int xic = min(max(xi, 0), FW - 1);
                const float wx = (dx ? tx : 1.f - tx) * (xin ? 1.f : 0.f);
                wcorn[2 * dy + dx] = wx * wy;
                pixc[2 * dy + dx]  = (cam * FH + yic) * FW + xic;
            }
        }

        // depth taps from transposed depth_T[d][pix]: lane handles corner
        // (s&3); x-adjacent corners share a 64B segment -> fewer requests
        const int kc = s & 3;
        const float t0 = depth_T[(size_t)zi0 * NPIX + pixc[kc]];
        const float t1 = depth_T[(size_t)zi1 * NPIX + pixc[kc]];
        const float wl = wcorn[kc] * (wz0 * t0 + wz1 * t1);
        const float w0 = __shfl(wl, gb | 0);
        const float w1 = __shfl(wl, gb | 1);
        const float w2 = __shfl(wl, gb | 2);
        const float w3 = __shfl(wl, gb | 3);
        const float wcs[4] = {w0, w1, w2, w3};

        // feat: per corner, 8-lane group reads 256B contiguous (2x float4)
        #pragma unroll
        for (int k = 0; k < 4; ++k) {
            const float wc = wcs[k];
            const float* fb = feat_t + (size_t)pixc[k] * CCH + s * 4;
            const float4 fa = *(const float4*)(fb);
            const float4 fh = *(const float4*)(fb + 32);
            acc[0] += wc * fa.x; acc[1] += wc * fa.y;
            acc[2] += wc * fa.z; acc[3] += wc * fa.w;
            acc[4] += wc * fh.x; acc[5] += wc * fh.y;
            acc[6] += wc * fh.z; acc[7] += wc * fh.w;
        }
    }

    // ---- Stage 3: LDS transpose -> full-line coalesced stores ------------
    const float invc = cnt > 0.f ? 1.f / cnt : 0.f;
    #pragma unroll
    for (int j = 0; j < 4; ++j) {
        trans[(4 * s + j) * 33 + w * 8 + g]      = acc[j]     * invc;
        trans[(32 + 4 * s + j) * 33 + w * 8 + g] = acc[4 + j] * invc;
    }
    __syncthreads();
    {
        const int idx = t & 31;           // 4 iy x 8 iz = one 128B line
        const int cb  = t >> 5;           // 0..7
        const size_t obase = (size_t)ix * (NY * NZ) + iy0 * 8 + idx;
        #pragma unroll
        for (int i = 0; i < 8; ++i) {
            const int c = cb + 8 * i;
            out[(size_t)c * NPTS + obase] = trans[c * 33 + idx];
        }
    }
}

extern "C" void kernel_launch(void* const* d_in, const int* in_sizes, int n_in,
                              void* d_out, int out_size, void* d_ws, size_t ws_size,
                              hipStream_t stream) {
    const float* x_fov = (const float*)d_in[0];   // (1,6,64,32,88)
    const float* w_dn  = (const float*)d_in[1];   // (130,64)
    const float* b_dn  = (const float*)d_in[2];   // (130,)
    const float* proj  = (const float*)d_in[4];   // (1,6,4,4)
    float* out = (float*)d_out;                   // (1,64,128,128,8)

    float* feat_t  = (float*)d_ws;                            // [NPIX][64]
    float* depth_T = feat_t + (size_t)NPIX * CCH;             // [66][NPIX]

    depthnet_kernel<<<132, 256, 0, stream>>>(x_fov, w_dn, b_dn, feat_t, depth_T);

    // 4096 blocks x 4 waves; wave = one (ix,iy) column (8 iz) x 8 lanes
    splat_kernel<<<(NX * NY) / 4, 256, 0, stream>>>(feat_t, depth_T, proj, out);
}

// Round 9
// 102.467 us; speedup vs baseline: 1.4450x; 1.4450x over previous
//
#include <hip/hip_runtime.h>
#include <math.h>

#define NCAM 6
#define CCH  64
#define DB   66
#define FH   32
#define FW   88
#define NX   128
#define NY   128
#define NZ   8
#define NPTS (NX*NY*NZ)
#define NPIX (NCAM*FH*FW)
#define PPC  (FH*FW)          // pixels per camera = 2816

// ---- depthnet v3 tiling ----
#define TPX   32              // pixels per block (2816 % 32 == 0) -> 528 blocks
#define DN_T  256
#define WS2   132             // wT row stride
#define YSS   35              // ys row stride (conflict-tuned)
#define OFF_XS 0              // xs[64][32]   = 2048
#define OFF_WT 2048           // wT[64][132]  = 8448 (end 10496)
#define OFF_YS 2048           // ys[130][35]  = 4550 alias wT (end 6598)
#define OFF_BS 10496          // bias[130]    (end 10626)
#define LDS_F  10626

// ---------------------------------------------------------------------------
// Kernel 1 (v3, known-good): tiled depth-net. Block = 32 contiguous
// pixels of one camera. Stage x[64c][32px] + w^T[64c][130] in LDS; 8px x
// 2out register tiles; softmax 8 lanes/pixel, static-indexed exp registers.
// ---------------------------------------------------------------------------
__global__ __launch_bounds__(DN_T) void depthnet_kernel(
    const float* __restrict__ x_fov, const float* __restrict__ w_dn,
    const float* __restrict__ b_dn, float* __restrict__ feat_t,
    float* __restrict__ depth_t)
{
    __shared__ float lds[LDS_F];
    float* xs = lds + OFF_XS;
    float* wT = lds + OFF_WT;
    float* ys = lds + OFF_YS;   // aliases wT (dead after phase B)
    float* bs = lds + OFF_BS;

    const int t   = threadIdx.x;
    const int T   = blockIdx.x * TPX;       // global pixel base
    const int cam = T / PPC;
    const int ph0 = T - cam * PPC;

    // ---- Phase A: stage bias, w^T, x tile --------------------------------
    if (t < DB + CCH) bs[t] = b_dn[t];
    for (int i = t; i < (DB + CCH) * CCH; i += DN_T) {
        const int o = i >> 6, c = i & 63;
        wT[c * WS2 + o] = w_dn[i];
    }
    {
        const float* xb = x_fov + (size_t)cam * CCH * PPC + ph0;
        const int c = t >> 2;               // 0..63
        const int q = t & 3;
        #pragma unroll
        for (int h = 0; h < 2; ++h) {
            const float4 v = *(const float4*)(xb + c * PPC + h * 16 + q * 4);
            *(float4*)(xs + c * TPX + h * 16 + q * 4) = v;
        }
    }
    __syncthreads();

    // ---- Phase B: y = w x, 8px x 2out per thread -------------------------
    const int pq = t & 3;
    const int oq = t >> 2;                  // outputs {2oq, 2oq+1}
    float acc[2][8];
    float acc2[2][8];                       // oq==0: outputs 128,129
    #pragma unroll
    for (int a = 0; a < 2; ++a)
        #pragma unroll
        for (int p = 0; p < 8; ++p) { acc[a][p] = 0.f; acc2[a][p] = 0.f; }

    {
        const float* xr  = xs + pq * 8;
        const float* wr  = wT + oq * 2;
        const float* wr2 = wT + 128;
        #pragma unroll 4
        for (int c = 0; c < 64; ++c) {
            const float4 xa = *(const float4*)(xr + c * TPX);
            const float4 xb2 = *(const float4*)(xr + c * TPX + 4);
            const float2 wv = *(const float2*)(wr + c * WS2);
            const float xv[8] = {xa.x, xa.y, xa.z, xa.w, xb2.x, xb2.y, xb2.z, xb2.w};
            #pragma unroll
            for (int p = 0; p < 8; ++p) {
                acc[0][p] += wv.x * xv[p];
                acc[1][p] += wv.y * xv[p];
            }
            if (oq == 0) {
                const float2 w2 = *(const float2*)(wr2 + c * WS2);
                #pragma unroll
                for (int p = 0; p < 8; ++p) {
                    acc2[0][p] += w2.x * xv[p];
                    acc2[1][p] += w2.y * xv[p];
                }
            }
        }
    }
    __syncthreads();   // wT reads done; ys may overwrite

    // ---- Phase C: y (+bias) -> LDS ys[o][px] -----------------------------
    #pragma unroll
    for (int a = 0; a < 2; ++a) {
        const int o = 2 * oq + a;
        const float b = bs[o];
        #pragma unroll
        for (int p = 0; p < 8; ++p) ys[o * YSS + pq * 8 + p] = acc[a][p] + b;
    }
    if (oq == 0) {
        #pragma unroll
        for (int a = 0; a < 2; ++a) {
            const int o = 128 + a;
            const float b = bs[o];
            #pragma unroll
            for (int p = 0; p < 8; ++p) ys[o * YSS + pq * 8 + p] = acc2[a][p] + b;
        }
    }
    __syncthreads();

    // ---- Phase D: softmax, 8 lanes/pixel, static-indexed exp registers ---
    {
        const int spx = t >> 3;
        const int r   = t & 7;
        float m = -1e30f;
        #pragma unroll
        for (int i = 0; i < 9; ++i) {
            const int o = r + 8 * i;
            if (o < DB) m = fmaxf(m, ys[o * YSS + spx]);
        }
        m = fmaxf(m, __shfl_xor(m, 1));
        m = fmaxf(m, __shfl_xor(m, 2));
        m = fmaxf(m, __shfl_xor(m, 4));
        float e[9];
        float ssum = 0.f;
        #pragma unroll
        for (int i = 0; i < 9; ++i) {
            const int o = r + 8 * i;
            const float v = (o < DB) ? expf(ys[o * YSS + spx] - m) : 0.f;
            e[i] = v;
            ssum += v;
        }
        ssum += __shfl_xor(ssum, 1);
        ssum += __shfl_xor(ssum, 2);
        ssum += __shfl_xor(ssum, 4);
        const float inv = 1.f / ssum;
        #pragma unroll
        for (int i = 0; i < 9; ++i) {
            const int o = r + 8 * i;
            if (o < DB) depth_t[(size_t)(T + spx) * DB + o] = e[i] * inv;
        }
    }

    // ---- Phase E: coalesced feat stores ----------------------------------
    for (int i = t; i < TPX * CCH; i += DN_T) {
        const int px = i >> 6, o = i & 63;
        feat_t[(size_t)T * CCH + i] = ys[(DB + o) * YSS + px];
    }
}

// ---------------------------------------------------------------------------
// Kernel 2 v5: wave = 8 points (one (ix,iy) column, g = iz) x 8 lanes.
// PHASE 1 (latency-hoisted): lane s projects its group's point into camera
// s AND computes all 4 corners + all 8 depth taps + 4 corner weights for
// that camera -- every camera's depth loads are in flight simultaneously,
// off the per-camera critical path.
// PHASE 2: per camera (ballot-gated per group), shuffle the precomputed
// (pixc, wcs) and do the 8-lane-shared 256B-contiguous feat gathers.
// Block = 4 consecutive iy at one ix; LDS transpose -> full-128B-line stores.
// ---------------------------------------------------------------------------
__global__ __launch_bounds__(256) void splat_kernel(
    const float* __restrict__ feat_t, const float* __restrict__ depth_t,
    const float* __restrict__ proj, float* __restrict__ out)
{
    __shared__ float trans[64 * 33];      // 8448 B, +1-pad stride
    const int t    = threadIdx.x;
    const int w    = t >> 6;              // wave in block: iy offset 0..3
    const int lane = t & 63;
    const int g    = lane >> 3;           // iz
    const int s    = lane & 7;            // sub-lane (= camera in phase 1)
    const int gb   = lane & 56;           // group base lane
    const int ix   = blockIdx.x >> 5;     // 0..127
    const int iy0  = 4 * (blockIdx.x & 31);
    const int iy   = iy0 + w;

    // bit-exact numpy voxel-center grid (double -> float)
    const double DXY = 102.4 / 128.0;
    const float px = (float)(-51.2 + (ix + 0.5) * DXY);
    const float py = (float)(-51.2 + (iy + 0.5) * DXY);
    const float pz = (float)(-5.0 + (g + 0.5) * 1.0);

    // ---- Phase 1: lane s = camera s; full corner+depth precompute --------
    float wcs_l[4] = {0.f, 0.f, 0.f, 0.f};
    int   pixc_l[4] = {0, 0, 0, 0};
    bool validm = false;
    if (s < NCAM) {
        const float* M = proj + s * 16;
        const float u4 = M[0] * px + M[1] * py + M[2]  * pz + M[3];
        const float v4 = M[4] * px + M[5] * py + M[6]  * pz + M[7];
        const float z  = M[8] * px + M[9] * py + M[10] * pz + M[11];
        const float zs = fabsf(z) > 0.001f ? z : 0.001f;
        const float u = u4 / zs;
        const float v = v4 / zs;
        validm = (u >= 0.f) && (u < 1408.f) && (v >= 0.f) && (v < 512.f) &&
                 (z > 0.f) && (z < 50.f);
        if (validm) {
            const float gx = u / 1408.0f * (float)FW - 0.5f;
            const float gy = v / 512.0f  * (float)FH - 0.5f;
            const float gz = z / 50.0f   * (float)DB - 0.5f;
            const float xf = floorf(gx), yf = floorf(gy), zf = floorf(gz);
            const float tx = gx - xf, ty = gy - yf, tz = gz - zf;
            const int x0 = (int)xf, y0 = (int)yf, z0 = (int)zf;

            const float wz0 = (z0 >= 0 && z0 < DB) ? (1.f - tz) : 0.f;
            const float wz1 = (z0 + 1 < DB) ? tz : 0.f;
            const int zi0 = min(max(z0, 0), DB - 1);
            const int zi1 = min(max(z0 + 1, 0), DB - 1);

            #pragma unroll
            for (int dy = 0; dy < 2; ++dy) {
                const int yi = y0 + dy;
                const bool yin = (yi >= 0) & (yi < FH);
                const int yic = min(max(yi, 0), FH - 1);
                const float wy = (dy ? ty : 1.f - ty) * (yin ? 1.f : 0.f);
                #pragma unroll
                for (int dx = 0; dx < 2; ++dx) {
                    const int xi = x0 + dx;
                    const bool xin = (xi >= 0) & (xi < FW);
                    const int xic = min(max(xi, 0), FW - 1);
                    const float wx = (dx ? tx : 1.f - tx) * (xin ? 1.f : 0.f);
                    pixc_l[2 * dy + dx] = (s * FH + yic) * FW + xic;
                    wcs_l[2 * dy + dx]  = wx * wy;
                }
            }
            // all 8 depth taps issued here: independent across lanes/cams
            #pragma unroll
            for (int k = 0; k < 4; ++k) {
                const float* dptr = depth_t + (size_t)pixc_l[k] * DB;
                wcs_l[k] *= wz0 * dptr[zi0] + wz1 * dptr[zi1];
            }
        }
    }
    const unsigned long long bal = __ballot(validm);
    const float cnt = (float)__popcll((bal >> (g * 8)) & 0x3Full);

    float acc[8];
    #pragma unroll
    for (int a = 0; a < 8; ++a) acc[a] = 0.f;

    // ---- Phase 2: per camera, shuffle precomputed weights, gather feat ---
    for (int cam = 0; cam < NCAM; ++cam) {
        if ((bal >> (gb + cam)) & 1ull) {   // this group's cam valid
            #pragma unroll
            for (int k = 0; k < 4; ++k) {
                const float wc  = __shfl(wcs_l[k], gb | cam);
                const int   pcx = __shfl(pixc_l[k], gb | cam);
                const float* fb = feat_t + (size_t)pcx * CCH + s * 4;
                const float4 fa = *(const float4*)(fb);
                const float4 fh = *(const float4*)(fb + 32);
                acc[0] += wc * fa.x; acc[1] += wc * fa.y;
                acc[2] += wc * fa.z; acc[3] += wc * fa.w;
                acc[4] += wc * fh.x; acc[5] += wc * fh.y;
                acc[6] += wc * fh.z; acc[7] += wc * fh.w;
            }
        }
    }

    // ---- Phase 3: LDS transpose -> full-line coalesced stores ------------
    const float invc = cnt > 0.f ? 1.f / cnt : 0.f;
    #pragma unroll
    for (int j = 0; j < 4; ++j) {
        trans[(4 * s + j) * 33 + w * 8 + g]      = acc[j]     * invc;
        trans[(32 + 4 * s + j) * 33 + w * 8 + g] = acc[4 + j] * invc;
    }
    __syncthreads();
    {
        const int idx = t & 31;           // 4 iy x 8 iz = one 128B line
        const int cb  = t >> 5;           // 0..7
        const size_t obase = (size_t)ix * (NY * NZ) + iy0 * 8 + idx;
        #pragma unroll
        for (int i = 0; i < 8; ++i) {
            const int c = cb + 8 * i;
            out[(size_t)c * NPTS + obase] = trans[c * 33 + idx];
        }
    }
}

extern "C" void kernel_launch(void* const* d_in, const int* in_sizes, int n_in,
                              void* d_out, int out_size, void* d_ws, size_t ws_size,
                              hipStream_t stream) {
    const float* x_fov = (const float*)d_in[0];   // (1,6,64,32,88)
    const float* w_dn  = (const float*)d_in[1];   // (130,64)
    const float* b_dn  = (const float*)d_in[2];   // (130,)
    const float* proj  = (const float*)d_in[4];   // (1,6,4,4)
    float* out = (float*)d_out;                   // (1,64,128,128,8)

    float* feat_t  = (float*)d_ws;                            // [NPIX][64]
    float* depth_t = feat_t + (size_t)NPIX * CCH;             // [NPIX][66]

    depthnet_kernel<<<NPIX / TPX, DN_T, 0, stream>>>(x_fov, w_dn, b_dn, feat_t, depth_t);

    // 4096 blocks x 4 waves; wave = one (ix,iy) column (8 iz) x 8 lanes
    splat_kernel<<<(NX * NY) / 4, 256, 0, stream>>>(feat_t, depth_t, proj, out);
}